// Round 2
// baseline (17699.120 us; speedup 1.0000x reference)
//
#include <hip/hip_runtime.h>
#include <math.h>

#define T_ 512
#define B_ 64
#define IN_ 128
#define H_ 512
#define L_ 3
#define OUT_ 128

// ---- workspace layout (floats) ----
constexpr size_t OFF_BUF = 0;                            // T*B*H = 16,777,216
constexpr size_t OFF_WTH = (size_t)T_ * B_ * H_;         // 3 * H*H (W_hh^T per layer)
constexpr size_t OFF_WTI = OFF_WTH + 3ull * H_ * H_;     // 2 * H*H (W_ih_rest^T)
constexpr size_t OFF_WT0 = OFF_WTI + 2ull * H_ * H_;     // IN*H   (W_ih0^T)
constexpr size_t OFF_WTL = OFF_WT0 + (size_t)IN_ * H_;   // H*OUT  (lin_W^T)
// total ≈ 18,219,008 floats ≈ 69.5 MB

// Batched transpose: dst[c*R + r] = src[r*C + c]  (Wt layout = [K][N], coalesced over N)
__global__ void transpose_all(const float* __restrict__ whh,
                              const float* __restrict__ wihr,
                              const float* __restrict__ wih0,
                              const float* __restrict__ linw,
                              float* __restrict__ ws) {
    __shared__ float tile[32][33];
    const float* src; float* dst; int R, C;
    switch (blockIdx.z) {
        case 0: case 1: case 2: {
            int l = blockIdx.z;
            src = whh + (size_t)l * H_ * H_;
            dst = ws + OFF_WTH + (size_t)l * H_ * H_;
            R = H_; C = H_; break;
        }
        case 3: case 4: {
            int l = blockIdx.z - 3;
            src = wihr + (size_t)l * H_ * H_;
            dst = ws + OFF_WTI + (size_t)l * H_ * H_;
            R = H_; C = H_; break;
        }
        case 5:
            src = wih0; dst = ws + OFF_WT0; R = H_; C = IN_; break;  // -> [IN][H]
        default:
            src = linw; dst = ws + OFF_WTL; R = OUT_; C = H_; break; // -> [H][OUT]
    }
    int bx = blockIdx.x * 32;  // col offset in src
    int by = blockIdx.y * 32;  // row offset in src
    if (bx >= C || by >= R) return;
    for (int i = threadIdx.y; i < 32; i += 8) {
        int r = by + i, c = bx + threadIdx.x;
        if (r < R && c < C) tile[i][threadIdx.x] = src[(size_t)r * C + c];
    }
    __syncthreads();
    for (int i = threadIdx.y; i < 32; i += 8) {
        int c = bx + i, r = by + threadIdx.x;
        if (r < R && c < C) dst[(size_t)c * R + r] = tile[threadIdx.x][i];
    }
}

// Row-panel GEMM: Out[m][j] = sum_k In[m][k] * Wt[k][j] + bias[j]
// BM=16 rows per block, 512 threads. In-place safe (all In reads complete
// and land in LDS before the barrier; all Out writes are after it, and rows
// are partitioned exclusively across blocks).
template <int N, int K>
__global__ __launch_bounds__(512) void gemm_panel(const float* In,
                                                  const float* __restrict__ Wt,
                                                  const float* __restrict__ bias,
                                                  float* Out) {
    __shared__ float A[16 * K];
    const int tid = threadIdx.x;
    const size_t m0 = (size_t)blockIdx.x * 16;

    const float4* In4 = (const float4*)(In + m0 * K);
    float4* A4 = (float4*)A;
    #pragma unroll
    for (int i = tid; i < 16 * K / 4; i += 512) A4[i] = In4[i];
    __syncthreads();

    constexpr int TPN = 512 / N;   // threads stacked per column: 1 (N=512) or 4 (N=128)
    constexpr int RPT = 16 / TPN;  // rows per thread: 16 or 4
    const int j = tid % N;
    const int r0 = (tid / N) * RPT;

    float acc[RPT];
    const float bv = bias[j];
    #pragma unroll
    for (int r = 0; r < RPT; r++) acc[r] = bv;

    for (int k = 0; k < K; k += 4) {
        const float wv0 = Wt[(size_t)(k + 0) * N + j];
        const float wv1 = Wt[(size_t)(k + 1) * N + j];
        const float wv2 = Wt[(size_t)(k + 2) * N + j];
        const float wv3 = Wt[(size_t)(k + 3) * N + j];
        #pragma unroll
        for (int r = 0; r < RPT; r++) {
            const float4 av = *(const float4*)&A[(r0 + r) * K + k];
            acc[r] += av.x * wv0 + av.y * wv1 + av.z * wv2 + av.w * wv3;
        }
    }
    #pragma unroll
    for (int r = 0; r < RPT; r++) Out[(m0 + r0 + r) * N + j] = acc[r];
}

// Recurrence for one layer: one block per batch row, one thread per hidden unit.
// Iterates all T timesteps locally; h kept in LDS; no grid syncs needed.
// Reads pre-activation from buf[t] and overwrites it with the hidden output.
__global__ __launch_bounds__(512) void rnn_rec(float* buf,
                                               const float* __restrict__ WtH,  // [H][H] = W_hh^T
                                               const float* __restrict__ h0_l, // [B][H]
                                               const float* __restrict__ bhh,  // [H]
                                               float* __restrict__ hout) {     // [B][H]
    __shared__ float h[H_];
    const int b = blockIdx.x;
    const int j = threadIdx.x;

    h[j] = h0_l[b * H_ + j];
    const float bv = bhh[j];
    __syncthreads();

    for (int t = 0; t < T_; t++) {
        float acc = buf[((size_t)t * B_ + b) * H_ + j] + bv;
        #pragma unroll 2
        for (int k = 0; k < H_; k += 4) {
            const float4 hv = *(const float4*)&h[k];
            acc += hv.x * WtH[(size_t)(k + 0) * H_ + j];
            acc += hv.y * WtH[(size_t)(k + 1) * H_ + j];
            acc += hv.z * WtH[(size_t)(k + 2) * H_ + j];
            acc += hv.w * WtH[(size_t)(k + 3) * H_ + j];
        }
        const float hn = tanhf(acc);
        __syncthreads();
        h[j] = hn;
        buf[((size_t)t * B_ + b) * H_ + j] = hn;
        __syncthreads();
    }
    hout[b * H_ + j] = h[j];
}

extern "C" void kernel_launch(void* const* d_in, const int* in_sizes, int n_in,
                              void* d_out, int out_size, void* d_ws, size_t ws_size,
                              hipStream_t stream) {
    const float* x      = (const float*)d_in[0];
    const float* h0     = (const float*)d_in[1];
    const float* W_ih0  = (const float*)d_in[2];
    const float* W_ihr  = (const float*)d_in[3];
    const float* W_hh   = (const float*)d_in[4];
    const float* b_ih   = (const float*)d_in[5];
    const float* b_hh   = (const float*)d_in[6];
    const float* lin_W  = (const float*)d_in[7];
    const float* lin_b  = (const float*)d_in[8];
    float* out = (float*)d_out;
    float* ws  = (float*)d_ws;

    float* buf = ws + OFF_BUF;
    float* WtH = ws + OFF_WTH;
    float* WtI = ws + OFF_WTI;
    float* Wt0 = ws + OFF_WT0;
    float* WtL = ws + OFF_WTL;
    float* h_final = out + (size_t)T_ * B_ * OUT_;  // [L][B][H]

    constexpr int M = T_ * B_;  // 32768 rows

    // 1) transpose all weights into ws
    transpose_all<<<dim3(16, 16, 7), dim3(32, 8), 0, stream>>>(W_hh, W_ihr, W_ih0, lin_W, ws);

    // 2) layer 0: pre = x @ W_ih0^T + b_ih[0]
    gemm_panel<H_, IN_><<<M / 16, 512, 0, stream>>>(x, Wt0, b_ih + 0 * H_, buf);
    rnn_rec<<<B_, H_, 0, stream>>>(buf, WtH + 0 * (size_t)H_ * H_, h0 + 0 * B_ * H_,
                                   b_hh + 0 * H_, h_final + 0 * B_ * H_);

    // 3) layer 1 (in-place input projection over buf)
    gemm_panel<H_, H_><<<M / 16, 512, 0, stream>>>(buf, WtI + 0 * (size_t)H_ * H_,
                                                   b_ih + 1 * H_, buf);
    rnn_rec<<<B_, H_, 0, stream>>>(buf, WtH + 1 * (size_t)H_ * H_, h0 + 1 * B_ * H_,
                                   b_hh + 1 * H_, h_final + 1 * B_ * H_);

    // 4) layer 2
    gemm_panel<H_, H_><<<M / 16, 512, 0, stream>>>(buf, WtI + 1 * (size_t)H_ * H_,
                                                   b_ih + 2 * H_, buf);
    rnn_rec<<<B_, H_, 0, stream>>>(buf, WtH + 2 * (size_t)H_ * H_, h0 + 2 * B_ * H_,
                                   b_hh + 2 * H_, h_final + 2 * B_ * H_);

    // 5) out = ys2 @ lin_W^T + lin_b
    gemm_panel<OUT_, H_><<<M / 16, 512, 0, stream>>>(buf, WtL, lin_b, out);
}